// Round 4
// baseline (455.819 us; speedup 1.0000x reference)
//
#include <hip/hip_runtime.h>
#include <hip/hip_bf16.h>

#define B_N 8
#define C_IN 512
#define C_OUT 512
#define H_ 64
#define W_ 64
#define HW_ 4096
#define LAT_ 512

typedef __attribute__((ext_vector_type(8))) short bf8;
typedef __attribute__((ext_vector_type(4))) float f32x4;

__device__ inline ushort f2bf(float f) {
  uint u = __float_as_uint(f);
  uint r = (u + 0x7FFFu + ((u >> 16) & 1u)) >> 16;
  return (ushort)r;
}

// ---------------- style[b][cin]: one wave per output, shuffle reduce ----------------
__global__ void style_kernel(const float* __restrict__ latent,
                             const float* __restrict__ fcw,
                             const float* __restrict__ fcb,
                             float* __restrict__ style) {
  int gw = (blockIdx.x * 256 + threadIdx.x) >> 6;  // 0..4095
  int lane = threadIdx.x & 63;
  int b = gw >> 9, c = gw & 511;
  const float4* l4 = (const float4*)(latent + (size_t)b * LAT_);
  const float4* w4 = (const float4*)(fcw + (size_t)c * LAT_);
  float4 a0 = l4[lane * 2], a1 = l4[lane * 2 + 1];
  float4 f0 = w4[lane * 2], f1 = w4[lane * 2 + 1];
  float acc = a0.x * f0.x + a0.y * f0.y + a0.z * f0.z + a0.w * f0.w +
              a1.x * f1.x + a1.y * f1.y + a1.z * f1.z + a1.w * f1.w;
#pragma unroll
  for (int m = 32; m; m >>= 1) acc += __shfl_xor(acc, m, 64);
  if (lane == 0) style[gw] = acc * 0.04419417382415922f + fcb[c];
}

// ---------------- wcast: fragment-native bf16 weights + wsq, fused ----------------
// wbf2[((cinblk*9 + tap)*32 + cout/16)*1024 + (cout&15)*64 + (cin&63)]
__global__ void wcast_kernel(const float* __restrict__ w, ushort* __restrict__ wbf2,
                             float* __restrict__ wsq) {
  int idx = blockIdx.x * blockDim.x + threadIdx.x;  // cout*512 + cin
  int cout = idx >> 9, cin = idx & 511;
  const float* p = w + (size_t)idx * 9;
  int cinblk = cin >> 6, cl = cin & 63, cs = cout >> 4, r = cout & 15;
  float s = 0.f;
#pragma unroll
  for (int t = 0; t < 9; ++t) {
    float v = p[t];
    s += v * v;
    wbf2[(((size_t)cinblk * 9 + t) * 32 + cs) * 1024 + r * 64 + cl] = f2bf(v);
  }
  wsq[idx] = s;
}

// ---------------- demod: one wave per output, shuffle reduce ----------------
__global__ void demod_kernel(const float* __restrict__ style,
                             const float* __restrict__ wsq,
                             float* __restrict__ demod) {
  int gw = (blockIdx.x * 256 + threadIdx.x) >> 6;  // 0..4095
  int lane = threadIdx.x & 63;
  int b = gw >> 9, co = gw & 511;
  const float4* s4 = (const float4*)(style + (size_t)b * C_IN);
  const float4* w4 = (const float4*)(wsq + (size_t)co * C_IN);
  float4 s0 = s4[lane * 2], s1 = s4[lane * 2 + 1];
  float4 w0 = w4[lane * 2], w1 = w4[lane * 2 + 1];
  float acc = s0.x * s0.x * w0.x + s0.y * s0.y * w0.y + s0.z * s0.z * w0.z +
              s0.w * s0.w * w0.w + s1.x * s1.x * w1.x + s1.y * s1.y * w1.y +
              s1.z * s1.z * w1.z + s1.w * s1.w * w1.w;
#pragma unroll
  for (int m = 32; m; m >>= 1) acc += __shfl_xor(acc, m, 64);
  // fold w_mul_conv = sqrt(2)/sqrt(512*9) = 1/48
  if (lane == 0) demod[gw] = rsqrtf(acc + 1e-8f) * 0.020833333333333332f;
}

// ---------------- xm[b][h][w][cin] = bf16(x[b][cin][h][w] * style[b][cin]) ----------------
__global__ void xmod_kernel(const float* __restrict__ x,
                            const float* __restrict__ style,
                            ushort* __restrict__ xm) {
  __shared__ float t[64][65];
  int c0 = blockIdx.x * 64;
  int h = blockIdx.y;
  int b = blockIdx.z;
  int tid = threadIdx.x;
  int col = tid & 63;
  int rg = tid >> 6;
#pragma unroll
  for (int rr = 0; rr < 16; ++rr) {
    int r = rr * 4 + rg;
    t[r][col] = x[(((size_t)(b * C_IN + c0 + r)) * H_ + h) * W_ + col] *
                style[b * C_IN + c0 + r];
  }
  __syncthreads();
#pragma unroll
  for (int rr = 0; rr < 16; ++rr) {
    int w = rr * 4 + rg;
    xm[(((size_t)(b * H_ + h)) * W_ + w) * C_IN + c0 + col] = f2bf(t[col][w]);
  }
}

// ---------------- main conv ----------------
// A (weights) from global in fragment layout; B (pixels) in LDS, XOR-swizzled.
// Grid: flat 1024, XCD-swizzled so XCD k handles image k.
#define BCOLS 66

__global__ __launch_bounds__(256, 4)
void conv_kernel(const ushort* __restrict__ xm,
                 const ushort* __restrict__ wbf,
                 const float* __restrict__ demod,
                 const float* __restrict__ bias,
                 float* __restrict__ out) {
  __shared__ ushort Bs[4 * BCOLS * 64];  // 33,792 B

  const int tid = threadIdx.x;
  const int lane = tid & 63;
  const int wave = tid >> 6;
  const int wr = wave >> 1;  // cout 64-block
  const int wc = wave & 1;   // spatial 64-block (row within 2-row tile)
  const int l15 = lane & 15;
  const int kg = lane >> 4;
  const int sub = tid & 7;

  // XCD swizzle: consecutive blockIdx round-robin XCDs; give XCD k a
  // contiguous work range = exactly image k (xm slice 4MB ~ L2/XCD).
  int ln = blockIdx.x;
  int work = (ln & 7) * 128 + (ln >> 3);
  const int b = work >> 7;
  const int tile = (work >> 2) & 31;
  const int cout0 = (work & 3) * 128;
  const int r0 = tile * 2;

  f32x4 acc[4][4];
#pragma unroll
  for (int m = 0; m < 4; ++m)
#pragma unroll
    for (int n = 0; n < 4; ++n) acc[m][n] = (f32x4){0.f, 0.f, 0.f, 0.f};

  const ushort* xb = xm + (size_t)b * HW_ * C_IN;
  const bf8 zer = {0, 0, 0, 0, 0, 0, 0, 0};

  for (int cin0 = 0, cinblk = 0; cin0 < C_IN; cin0 += 64, ++cinblk) {
    __syncthreads();
    // ---- stage B: 4 halo rows x 64 cols x 64 cin, slot-swizzled ----
#pragma unroll
    for (int pass = 0; pass < 8; ++pass) {
      int pair = pass * 32 + (tid >> 3);
      int row = pair >> 6;
      int col = pair & 63;
      int gr = r0 - 1 + row;
      int dslot = sub ^ ((col + 1) & 7);
      bf8* dst = (bf8*)&Bs[((row * BCOLS + col + 1) * 8 + dslot) * 8];
      if ((unsigned)gr < 64u)
        *dst = *(const bf8*)&xb[((size_t)(gr * W_ + col)) * C_IN + cin0 + sub * 8];
      else
        *dst = zer;
    }
    if (tid < 64) {  // zero pad columns 0 and 65 (any slot perm of zeros ok)
      int row = tid >> 4;
      int col = ((tid >> 3) & 1) ? (BCOLS - 1) : 0;
      *(bf8*)&Bs[((row * BCOLS + col) * 8 + sub) * 8] = zer;
    }
    __syncthreads();

    // ---- 9 taps, no barriers: A-frags direct from global (L2/L3) ----
    const ushort* wcb = wbf +
        ((size_t)(cinblk * 9) * 32 + (cout0 >> 4) + wr * 4) * 1024 + l15 * 64 + kg * 8;
#pragma unroll
    for (int tap = 0; tap < 9; ++tap) {
      const int kh = tap / 3, kw = tap % 3;
      const ushort* wt = wcb + (size_t)tap * 32 * 1024;
#pragma unroll
      for (int ks = 0; ks < 2; ++ks) {
        bf8 af[4];
#pragma unroll
        for (int m = 0; m < 4; ++m) af[m] = *(const bf8*)&wt[m * 1024 + ks * 32];
#pragma unroll
        for (int n = 0; n < 4; ++n) {
          int colIdx = n * 16 + l15 + kw;  // LDS column (halo space)
          int slot = (ks * 4 + kg) ^ (colIdx & 7);
          bf8 bfr = *(const bf8*)&Bs[(((wc + kh) * BCOLS + colIdx) * 8 + slot) * 8];
#pragma unroll
          for (int m = 0; m < 4; ++m)
            acc[m][n] = __builtin_amdgcn_mfma_f32_16x16x32_bf16(
                af[m], bfr, acc[m][n], 0, 0, 0);
        }
      }
    }
  }

  // ---- epilogue: demod + bias + leaky relu ----
  const int pbase = tile * 128 + wc * 64;
#pragma unroll
  for (int m = 0; m < 4; ++m) {
#pragma unroll
    for (int r = 0; r < 4; ++r) {
      int co = cout0 + wr * 64 + m * 16 + kg * 4 + r;
      float d = demod[b * C_OUT + co];
      float bi = bias[co];
      float* op = out + ((size_t)(b * C_OUT + co)) * HW_ + pbase + l15;
#pragma unroll
      for (int n = 0; n < 4; ++n) {
        float v = acc[m][n][r] * d + bi;
        op[n * 16] = v > 0.f ? v : 0.2f * v;
      }
    }
  }
}

extern "C" void kernel_launch(void* const* d_in, const int* in_sizes, int n_in,
                              void* d_out, int out_size, void* d_ws, size_t ws_size,
                              hipStream_t stream) {
  const float* x = (const float*)d_in[0];
  const float* lat = (const float*)d_in[1];
  const float* wgt = (const float*)d_in[2];
  const float* bias = (const float*)d_in[3];
  const float* fcw = (const float*)d_in[4];
  const float* fcb = (const float*)d_in[5];
  float* out = (float*)d_out;

  char* ws = (char*)d_ws;
  ushort* xm = (ushort*)ws;                                   // 33,554,432 B
  ushort* wbf = (ushort*)(ws + 33554432);                     //  4,718,592 B
  float* style = (float*)(ws + 33554432 + 4718592);           //     16,384 B
  float* wsq = (float*)(ws + 33554432 + 4718592 + 16384);     //  1,048,576 B
  float* dem = (float*)(ws + 33554432 + 4718592 + 16384 + 1048576);

  style_kernel<<<1024, 256, 0, stream>>>(lat, fcw, fcb, style);
  wcast_kernel<<<1024, 256, 0, stream>>>(wgt, wbf, wsq);
  demod_kernel<<<1024, 256, 0, stream>>>(style, wsq, dem);
  xmod_kernel<<<dim3(8, 64, 8), 256, 0, stream>>>(x, style, xm);
  conv_kernel<<<1024, 256, 0, stream>>>(xm, wbf, dem, bias, out);
}

// Round 5
// 266.165 us; speedup vs baseline: 1.7125x; 1.7125x over previous
//
#include <hip/hip_runtime.h>
#include <hip/hip_bf16.h>

#define B_N 8
#define C_IN 512
#define C_OUT 512
#define H_ 64
#define W_ 64
#define HW_ 4096
#define LAT_ 512

// A-tile geometry: 64 cout rows x K=288 (9 taps * 32 cin), padded to 296
#define AKP 296
#define A_TILE_USH (64 * AKP)          // 18944 ushorts = 37888 B (37 KB-chunks of 1024B)
#define A_CHUNKS 37

typedef __attribute__((ext_vector_type(8))) short bf8;
typedef __attribute__((ext_vector_type(4))) float f32x4;

__device__ inline ushort f2bf(float f) {
  uint u = __float_as_uint(f);
  uint r = (u + 0x7FFFu + ((u >> 16) & 1u)) >> 16;
  return (ushort)r;
}

// ---------------- style[b][cin]: one wave per output, shuffle reduce ----------------
__global__ void style_kernel(const float* __restrict__ latent,
                             const float* __restrict__ fcw,
                             const float* __restrict__ fcb,
                             float* __restrict__ style) {
  int gw = (blockIdx.x * 256 + threadIdx.x) >> 6;  // 0..4095
  int lane = threadIdx.x & 63;
  int b = gw >> 9, c = gw & 511;
  const float4* l4 = (const float4*)(latent + (size_t)b * LAT_);
  const float4* w4 = (const float4*)(fcw + (size_t)c * LAT_);
  float4 a0 = l4[lane * 2], a1 = l4[lane * 2 + 1];
  float4 f0 = w4[lane * 2], f1 = w4[lane * 2 + 1];
  float acc = a0.x * f0.x + a0.y * f0.y + a0.z * f0.z + a0.w * f0.w +
              a1.x * f1.x + a1.y * f1.y + a1.z * f1.z + a1.w * f1.w;
#pragma unroll
  for (int m = 32; m; m >>= 1) acc += __shfl_xor(acc, m, 64);
  if (lane == 0) style[gw] = acc * 0.04419417382415922f + fcb[c];
}

// ---------------- wcast: packed padded A-tiles + wsq, fused ----------------
// wpk tile (cs, cinblk): [cout_local 64][k = tap*32 + cin_local, pad 296]
__global__ void wcast_kernel(const float* __restrict__ w, ushort* __restrict__ wpk,
                             float* __restrict__ wsq) {
  int idx = blockIdx.x * blockDim.x + threadIdx.x;  // cout*512 + cin
  int cout = idx >> 9, cin = idx & 511;
  const float* p = w + (size_t)idx * 9;
  int cs = cout >> 6, cl = cout & 63, cb = cin >> 5, ci = cin & 31;
  size_t base = (size_t)(cs * 16 + cb) * A_TILE_USH + cl * AKP + ci;
  float s = 0.f;
#pragma unroll
  for (int t = 0; t < 9; ++t) {
    float v = p[t];
    s += v * v;
    wpk[base + t * 32] = f2bf(v);
  }
  wsq[idx] = s;
}

// ---------------- demod: one wave per output, shuffle reduce ----------------
__global__ void demod_kernel(const float* __restrict__ style,
                             const float* __restrict__ wsq,
                             float* __restrict__ demod) {
  int gw = (blockIdx.x * 256 + threadIdx.x) >> 6;  // 0..4095
  int lane = threadIdx.x & 63;
  int b = gw >> 9, co = gw & 511;
  const float4* s4 = (const float4*)(style + (size_t)b * C_IN);
  const float4* w4 = (const float4*)(wsq + (size_t)co * C_IN);
  float4 s0 = s4[lane * 2], s1 = s4[lane * 2 + 1];
  float4 w0 = w4[lane * 2], w1 = w4[lane * 2 + 1];
  float acc = s0.x * s0.x * w0.x + s0.y * s0.y * w0.y + s0.z * s0.z * w0.z +
              s0.w * s0.w * w0.w + s1.x * s1.x * w1.x + s1.y * s1.y * w1.y +
              s1.z * s1.z * w1.z + s1.w * s1.w * w1.w;
#pragma unroll
  for (int m = 32; m; m >>= 1) acc += __shfl_xor(acc, m, 64);
  // fold w_mul_conv = sqrt(2)/sqrt(512*9) = 1/48
  if (lane == 0) demod[gw] = rsqrtf(acc + 1e-8f) * 0.020833333333333332f;
}

// ---------------- xm[b][h][w][cin] = bf16(x[b][cin][h][w] * style[b][cin]) ----------------
__global__ void xmod_kernel(const float* __restrict__ x,
                            const float* __restrict__ style,
                            ushort* __restrict__ xm) {
  __shared__ float t[64][65];
  int c0 = blockIdx.x * 64;
  int h = blockIdx.y;
  int b = blockIdx.z;
  int tid = threadIdx.x;
  int col = tid & 63;
  int rg = tid >> 6;
#pragma unroll
  for (int rr = 0; rr < 16; ++rr) {
    int r = rr * 4 + rg;
    t[r][col] = x[(((size_t)(b * C_IN + c0 + r)) * H_ + h) * W_ + col] *
                style[b * C_IN + c0 + r];
  }
  __syncthreads();
#pragma unroll
  for (int rr = 0; rr < 16; ++rr) {
    int w = rr * 4 + rg;
    xm[(((size_t)(b * H_ + h)) * W_ + w) * C_IN + c0 + col] = f2bf(t[col][w]);
  }
}

// ---------------- main conv ----------------
// Block: 64 cout x 256 px (4 rows x 64 cols), 4 waves (1 row each).
// Per 32-cin block: A (64x9taps x32cin) staged once via global_load_lds;
// B halo (6x66x32) reg-staged, XOR slot-swizzled. 9-tap loop barrier-free.
__global__ __launch_bounds__(256, 2)
void conv_kernel(const ushort* __restrict__ xm,
                 const ushort* __restrict__ wpk,
                 const float* __restrict__ demod,
                 const float* __restrict__ bias,
                 float* __restrict__ out) {
  __shared__ ushort As[A_TILE_USH];       // 37,888 B
  __shared__ ushort Bs[6 * 66 * 32];      // 25,344 B

  const int tid = threadIdx.x;
  const int lane = tid & 63;
  const int wave = tid >> 6;   // = output row within tile
  const int l15 = lane & 15;
  const int kg = lane >> 4;

  // XCD swizzle: XCD k handles image k (xm slice ~4MB in its L2).
  int ln = blockIdx.x;
  int work = (ln & 7) * 128 + (ln >> 3);
  const int b = work >> 7;          // image
  const int cs = (work >> 4) & 7;   // cout slice (64)
  const int rt = work & 15;         // row tile (4 rows)
  const int r0 = rt * 4;
  const int cout0 = cs * 64;

  f32x4 acc[4][4];
#pragma unroll
  for (int m = 0; m < 4; ++m)
#pragma unroll
    for (int n = 0; n < 4; ++n) acc[m][n] = (f32x4){0.f, 0.f, 0.f, 0.f};

  const ushort* xb = xm + (size_t)b * HW_ * C_IN;
  const bf8 zer = {0, 0, 0, 0, 0, 0, 0, 0};

  for (int cb = 0; cb < 16; ++cb) {
    if (cb) __syncthreads();  // previous compute done before overwriting LDS

    // ---- A: 37 x 1KB async copies, linear dst (wave-uniform base + lane*16) ----
    {
      const char* tile = (const char*)(wpk + (size_t)(cs * 16 + cb) * A_TILE_USH);
#pragma unroll
      for (int j = wave; j < A_CHUNKS; j += 4) {
        const char* gp = tile + j * 1024 + lane * 16;
        __builtin_amdgcn_global_load_lds(
            (const __attribute__((address_space(1))) void*)gp,
            (__attribute__((address_space(3))) void*)&As[j * 512], 16, 0, 0);
      }
    }

    // ---- B halo: 6 rows x 64 cols x 32 cin, slot-swizzled; 6 chunks/thread ----
#pragma unroll
    for (int i = 0; i < 6; ++i) {
      int c = i * 256 + tid;        // 0..1535
      int pix = c >> 2, sub = c & 3;
      int row = pix >> 6, col = pix & 63;
      int gr = r0 - 1 + row;
      int lc = col + 1;             // LDS column (halo space)
      bf8* dst = (bf8*)&Bs[(((row * 66 + lc) << 2) + (sub ^ (lc & 3))) * 8];
      if ((unsigned)gr < 64u)
        *dst = *(const bf8*)&xb[((size_t)(gr * W_ + col)) * C_IN + cb * 32 + sub * 8];
      else
        *dst = zer;
    }
    if (tid < 48) {  // zero halo cols 0 and 65
      int row = tid >> 3;
      int col = ((tid >> 2) & 1) ? 65 : 0;
      int slot = tid & 3;
      *(bf8*)&Bs[(((row * 66 + col) << 2) + slot) * 8] = zer;
    }

    __syncthreads();  // drains vmcnt (A copies) + lgkm (B writes)

    // ---- 9 taps, no barriers ----
#pragma unroll
    for (int tap = 0; tap < 9; ++tap) {
      const int kh = tap / 3, kw = tap % 3;
      bf8 af[4], bfr[4];
#pragma unroll
      for (int m = 0; m < 4; ++m)
        af[m] = *(const bf8*)&As[(m * 16 + l15) * AKP + tap * 32 + kg * 8];
#pragma unroll
      for (int n = 0; n < 4; ++n) {
        int colIdx = n * 16 + l15 + kw;
        int slot = kg ^ (colIdx & 3);
        bfr[n] = *(const bf8*)&Bs[((((wave + kh) * 66 + colIdx) << 2) + slot) * 8];
      }
#pragma unroll
      for (int m = 0; m < 4; ++m)
#pragma unroll
        for (int n = 0; n < 4; ++n)
          acc[m][n] = __builtin_amdgcn_mfma_f32_16x16x32_bf16(
              af[m], bfr[n], acc[m][n], 0, 0, 0);
    }
  }

  // ---- epilogue: demod + bias + leaky relu ----
#pragma unroll
  for (int m = 0; m < 4; ++m) {
#pragma unroll
    for (int r = 0; r < 4; ++r) {
      int co = cout0 + m * 16 + kg * 4 + r;
      float d = demod[b * C_OUT + co];
      float bi = bias[co];
      float* op = out + ((size_t)(b * C_OUT + co)) * HW_ + (r0 + wave) * W_ + l15;
#pragma unroll
      for (int n = 0; n < 4; ++n) {
        float v = acc[m][n][r] * d + bi;
        op[n * 16] = v > 0.f ? v : 0.2f * v;
      }
    }
  }
}

extern "C" void kernel_launch(void* const* d_in, const int* in_sizes, int n_in,
                              void* d_out, int out_size, void* d_ws, size_t ws_size,
                              hipStream_t stream) {
  const float* x = (const float*)d_in[0];
  const float* lat = (const float*)d_in[1];
  const float* wgt = (const float*)d_in[2];
  const float* bias = (const float*)d_in[3];
  const float* fcw = (const float*)d_in[4];
  const float* fcb = (const float*)d_in[5];
  float* out = (float*)d_out;

  char* ws = (char*)d_ws;
  ushort* xm = (ushort*)ws;                                  // 33,554,432 B
  ushort* wpk = (ushort*)(ws + 33554432);                    //  4,849,664 B (8*16*37888)
  float* style = (float*)(ws + 33554432 + 4849664);          //     16,384 B
  float* wsq = (float*)(ws + 33554432 + 4849664 + 16384);    //  1,048,576 B
  float* dem = (float*)(ws + 33554432 + 4849664 + 16384 + 1048576);

  style_kernel<<<1024, 256, 0, stream>>>(lat, fcw, fcb, style);
  wcast_kernel<<<1024, 256, 0, stream>>>(wgt, wpk, wsq);
  demod_kernel<<<1024, 256, 0, stream>>>(style, wsq, dem);
  xmod_kernel<<<dim3(8, 64, 8), 256, 0, stream>>>(x, style, xm);
  conv_kernel<<<1024, 256, 0, stream>>>(xm, wpk, dem, bias, out);
}